// Round 1
// baseline (287.389 us; speedup 1.0000x reference)
//
#include <hip/hip_runtime.h>
#include <hip/hip_cooperative_groups.h>

namespace cg = cooperative_groups;

// Attn_60705067761886: out = softmax((enc @ W^T + b) @ h), S=32768, H=1024, fp32.
//
// Algebra: energies = enc @ (W^T h) + (b.h); the scalar b.h cancels in softmax -> b unused.
//
// Single cooperative dispatch (256 blocks x 512 threads, co-resident):
//   Phase A: all blocks compute partials of v = W^T h  (k-split x j-split, 16 KiB W per block)
//   sync  -> Phase B: each wave sums 4 partials into its v fragment, streams 128 enc rows
//            (134 MiB, the HBM-bound phase), e kept in LDS (no global round-trip)
//   sync  -> global max over 256 block maxima; exp + block-local sums
//   sync  -> global sum; scaled write of out. No single-block softmax dispatch, no
//            inter-dispatch graph gaps, K1 runs on all 256 CUs.

#define H 1024
#define S 32768
#define NB 256         // blocks (1 per CU, co-resident for cooperative launch)
#define NT 512         // threads per block (8 waves)
#define RPB (S / NB)   // 128 rows per block

__global__ __launch_bounds__(NT) void fused_attn(const float* __restrict__ W,
                                                 const float* __restrict__ h,
                                                 const float* __restrict__ enc,
                                                 float* __restrict__ out,
                                                 float* __restrict__ ws) {
    cg::grid_group grid = cg::this_grid();
    __shared__ float sh[RPB];   // phase A: cross-wave reduce; phase B+: this block's 128 energies
    __shared__ float red[16];

    const int b    = blockIdx.x;
    const int t    = threadIdx.x;
    const int lane = t & 63;
    const int wave = t >> 6;    // 0..7

    float* vpart = ws;               // [4][H] partial v, by j-group
    float* wmax  = ws + 4 * H;       // [NB] block maxima
    float* wsum  = ws + 4 * H + NB;  // [NB] block exp-sums
    // All ws regions are fully written before being read -> poison-safe.

    // ---- Phase A: vpart[jg][k] = sum_{j in 256-row group jg} W[j][k] * h[j] ----
    // Block b = 4*kb + jg owns columns [16kb,16kb+16) x rows [256jg, 256jg+256).
    // One wave load = 4 j-rows x 16 consecutive k = 4 full 64B cachelines.
    {
        const int kb = b >> 2;
        const int jg = b & 3;
        const int k0 = kb * 16;
        const int kk = t & 15;
        const int jj = t >> 4;  // 0..31 across the block
        const float* Wp = W + (size_t)(jg * 256 + jj) * H + k0 + kk;
        const float* hp = h + jg * 256 + jj;
        float a0 = 0.f, a1 = 0.f;
#pragma unroll
        for (int i = 0; i < 8; i += 2) {
            a0 = fmaf(Wp[(size_t)(32 * i) * H],       hp[32 * i],       a0);
            a1 = fmaf(Wp[(size_t)(32 * (i + 1)) * H], hp[32 * (i + 1)], a1);
        }
        float a = a0 + a1;
        // sum the 4 jj residues within the wave (lane bits 4,5)
        a += __shfl_xor(a, 16, 64);
        a += __shfl_xor(a, 32, 64);
        if (lane < 16) sh[wave * 16 + lane] = a;   // sh[0..128)
        __syncthreads();
        if (t < 16) {
            float s = 0.f;
#pragma unroll
            for (int wv = 0; wv < 8; ++wv) s += sh[wv * 16 + t];
            vpart[jg * H + k0 + t] = s;
        }
    }
    grid.sync();

    // ---- Phase B: v fragment (sum of 4 partials), then e[row] = enc[row].v ----
    const int lane4 = lane * 4;
    float4 vf[4];
#pragma unroll
    for (int tt = 0; tt < 4; ++tt) {
        float4 s0 = *(const float4*)(vpart + 0 * H + tt * 256 + lane4);
        float4 s1 = *(const float4*)(vpart + 1 * H + tt * 256 + lane4);
        float4 s2 = *(const float4*)(vpart + 2 * H + tt * 256 + lane4);
        float4 s3 = *(const float4*)(vpart + 3 * H + tt * 256 + lane4);
        vf[tt].x = (s0.x + s1.x) + (s2.x + s3.x);
        vf[tt].y = (s0.y + s1.y) + (s2.y + s3.y);
        vf[tt].z = (s0.z + s1.z) + (s2.z + s3.z);
        vf[tt].w = (s0.w + s1.w) + (s2.w + s3.w);
    }

    // 16 rows per wave, 4 iterations x 4 rows; 16 coalesced dwordx4 loads in
    // flight per thread per iteration (same structure as the proven K2).
#pragma unroll
    for (int it = 0; it < 4; ++it) {
        const int lrow = wave * 16 + it * 4;           // 0..127 within block
        const float* rp = enc + (size_t)(b * RPB + lrow) * H + lane4;
        float4 a[4][4];
#pragma unroll
        for (int r = 0; r < 4; ++r)
#pragma unroll
            for (int tt = 0; tt < 4; ++tt)
                a[r][tt] = *(const float4*)(rp + (size_t)r * H + tt * 256);
#pragma unroll
        for (int r = 0; r < 4; ++r) {
            float s = 0.f;
#pragma unroll
            for (int tt = 0; tt < 4; ++tt) {
                s = fmaf(a[r][tt].x, vf[tt].x, s);
                s = fmaf(a[r][tt].y, vf[tt].y, s);
                s = fmaf(a[r][tt].z, vf[tt].z, s);
                s = fmaf(a[r][tt].w, vf[tt].w, s);
            }
#pragma unroll
            for (int off = 32; off >= 1; off >>= 1)
                s += __shfl_xor(s, off, 64);
            if (lane == 0) sh[lrow + r] = s;
        }
    }
    __syncthreads();

    // ---- block-local max over the 128 energies ----
    {
        float lm = (t < RPB) ? sh[t] : -3.0e38f;
#pragma unroll
        for (int off = 32; off >= 1; off >>= 1)
            lm = fmaxf(lm, __shfl_xor(lm, off, 64));
        if (lane == 0) red[wave] = lm;
        __syncthreads();
        if (t == 0) {
            float m = red[0];
#pragma unroll
            for (int wv = 1; wv < 8; ++wv) m = fmaxf(m, red[wv]);
            wmax[b] = m;
        }
    }
    grid.sync();

    // ---- global max (every block reduces the 256 block maxima; 1 KiB, L2-hit) ----
    float gm;
    {
        float m = (t < NB) ? wmax[t] : -3.0e38f;
#pragma unroll
        for (int off = 32; off >= 1; off >>= 1)
            m = fmaxf(m, __shfl_xor(m, off, 64));
        if (lane == 0) red[wave] = m;
        __syncthreads();
        if (t == 0) {
            float mm = red[0];
#pragma unroll
            for (int wv = 1; wv < 8; ++wv) mm = fmaxf(mm, red[wv]);
            red[8] = mm;    // broadcast slot (red[0..7] reused below, red[8] safe)
        }
        __syncthreads();
        gm = red[8];
    }

    // ---- exp + block-local sum ----
    {
        float p = 0.f;
        if (t < RPB) {
            p = __expf(sh[t] - gm);
            sh[t] = p;      // same-thread slot; re-read only by this thread
        }
        float s = p;
#pragma unroll
        for (int off = 32; off >= 1; off >>= 1)
            s += __shfl_xor(s, off, 64);
        if (lane == 0) red[wave] = s;   // red[0..7]; red[8] (gm) untouched
        __syncthreads();
        if (t == 0) {
            float Z = red[0];
#pragma unroll
            for (int wv = 1; wv < 8; ++wv) Z += red[wv];
            wsum[b] = Z;
        }
    }
    grid.sync();

    // ---- global sum + scaled write ----
    {
        float z = (t < NB) ? wsum[t] : 0.f;
#pragma unroll
        for (int off = 32; off >= 1; off >>= 1)
            z += __shfl_xor(z, off, 64);
        if (lane == 0) red[wave] = z;
        __syncthreads();
        if (t == 0) {
            float Z = red[0];
#pragma unroll
            for (int wv = 1; wv < 8; ++wv) Z += red[wv];
            red[8] = 1.0f / Z;
        }
        __syncthreads();
        const float inv = red[8];
        if (t < RPB) out[b * RPB + t] = sh[t] * inv;
    }
}

// ================= fallback path (previous 3-dispatch version) =================

__global__ __launch_bounds__(256) void matvec_v(const float* __restrict__ W,
                                                const float* __restrict__ h,
                                                float* __restrict__ v) {
    __shared__ float sh[64];
    const int t    = threadIdx.x;
    const int kk   = t & 15;
    const int jj   = t >> 4;
    const int w    = t >> 6;
    const int lane = t & 63;
    const int k0   = blockIdx.x * 16;

    const float* Wp = W + (size_t)jj * H + k0 + kk;
    float a0 = 0.f, a1 = 0.f;
#pragma unroll
    for (int i = 0; i < 64; i += 2) {
        a0 = fmaf(Wp[(size_t)(16 * i) * H],       h[16 * i + jj],       a0);
        a1 = fmaf(Wp[(size_t)(16 * (i + 1)) * H], h[16 * (i + 1) + jj], a1);
    }
    float a = a0 + a1;
    a += __shfl_xor(a, 16, 64);
    a += __shfl_xor(a, 32, 64);
    if (lane < 16) sh[w * 16 + lane] = a;
    __syncthreads();
    if (t < 16) v[k0 + t] = sh[t] + sh[t + 16] + sh[t + 32] + sh[t + 48];
}

__global__ __launch_bounds__(256) void energies_kernel(const float* __restrict__ enc,
                                                       const float* __restrict__ v,
                                                       float* __restrict__ e) {
    const int wave  = threadIdx.x >> 6;
    const int lane  = threadIdx.x & 63;
    const int lane4 = lane * 4;

    float4 vf[4];
#pragma unroll
    for (int t = 0; t < 4; ++t)
        vf[t] = *(const float4*)(v + t * 256 + lane4);

    const int row0 = (blockIdx.x * 4 + wave) * 4;
    const float* rp = enc + (size_t)row0 * H + lane4;

    float4 a[4][4];
#pragma unroll
    for (int r = 0; r < 4; ++r)
#pragma unroll
        for (int t = 0; t < 4; ++t)
            a[r][t] = *(const float4*)(rp + (size_t)r * H + t * 256);

    float acc[4];
#pragma unroll
    for (int r = 0; r < 4; ++r) {
        float s = 0.f;
#pragma unroll
        for (int t = 0; t < 4; ++t) {
            s = fmaf(a[r][t].x, vf[t].x, s);
            s = fmaf(a[r][t].y, vf[t].y, s);
            s = fmaf(a[r][t].z, vf[t].z, s);
            s = fmaf(a[r][t].w, vf[t].w, s);
        }
#pragma unroll
        for (int off = 32; off >= 1; off >>= 1)
            s += __shfl_xor(s, off, 64);
        acc[r] = s;
    }
    if (lane == 0)
        *(float4*)(e + row0) = make_float4(acc[0], acc[1], acc[2], acc[3]);
}

__global__ __launch_bounds__(1024) void softmax_kernel(const float* __restrict__ e,
                                                       float* __restrict__ out) {
    __shared__ float red[16];
    const int t    = threadIdx.x;
    const int lane = t & 63;
    const int wv   = t >> 6;

    float4 x[8];
#pragma unroll
    for (int r = 0; r < 8; ++r)
        x[r] = *(const float4*)(e + 4 * t + 4096 * r);

    float m = -1e30f;
#pragma unroll
    for (int r = 0; r < 8; ++r)
        m = fmaxf(m, fmaxf(fmaxf(x[r].x, x[r].y), fmaxf(x[r].z, x[r].w)));
#pragma unroll
    for (int off = 32; off >= 1; off >>= 1)
        m = fmaxf(m, __shfl_xor(m, off, 64));
    if (lane == 0) red[wv] = m;
    __syncthreads();
    if (t < 16) {
        float mm = red[t];
#pragma unroll
        for (int off = 8; off >= 1; off >>= 1)
            mm = fmaxf(mm, __shfl_xor(mm, off, 64));
        if (t == 0) red[0] = mm;
    }
    __syncthreads();
    m = red[0];
    __syncthreads();

    float s = 0.f;
#pragma unroll
    for (int r = 0; r < 8; ++r) {
        x[r].x = __expf(x[r].x - m); s += x[r].x;
        x[r].y = __expf(x[r].y - m); s += x[r].y;
        x[r].z = __expf(x[r].z - m); s += x[r].z;
        x[r].w = __expf(x[r].w - m); s += x[r].w;
    }
#pragma unroll
    for (int off = 32; off >= 1; off >>= 1)
        s += __shfl_xor(s, off, 64);
    if (lane == 0) red[wv] = s;
    __syncthreads();
    if (t < 16) {
        float ss = red[t];
#pragma unroll
        for (int off = 8; off >= 1; off >>= 1)
            ss += __shfl_xor(ss, off, 64);
        if (t == 0) red[0] = ss;
    }
    __syncthreads();
    const float inv = 1.0f / red[0];

#pragma unroll
    for (int r = 0; r < 8; ++r) {
        float4 y;
        y.x = x[r].x * inv;
        y.y = x[r].y * inv;
        y.z = x[r].z * inv;
        y.w = x[r].w * inv;
        *(float4*)(out + 4 * t + 4096 * r) = y;
    }
}

extern "C" void kernel_launch(void* const* d_in, const int* in_sizes, int n_in,
                              void* d_out, int out_size, void* d_ws, size_t ws_size,
                              hipStream_t stream) {
    const float* h   = (const float*)d_in[0];  // [H]
    const float* enc = (const float*)d_in[1];  // [S, H]
    const float* W   = (const float*)d_in[2];  // [H, H]
    // d_in[3] = b: unused -- b.h is constant over S, cancels in softmax.

    float* out = (float*)d_out;                // [S]
    float* ws  = (float*)d_ws;                 // 4*H + 2*NB floats used

    void* args[] = {(void*)&W, (void*)&h, (void*)&enc, (void*)&out, (void*)&ws};
    hipError_t err = hipLaunchCooperativeKernel((void*)fused_attn, dim3(NB), dim3(NT),
                                                args, 0, stream);
    if (err != hipSuccess) {
        // Fallback: proven 3-dispatch path (v = ws[0:H], e = ws[H:H+S]).
        float* v = ws;
        float* e = ws + H;
        matvec_v<<<64, 256, 0, stream>>>(W, h, v);
        energies_kernel<<<S / 16, 256, 0, stream>>>(enc, v, e);
        softmax_kernel<<<1, 1024, 0, stream>>>(e, out);
    }
}

// Round 2
// 202.354 us; speedup vs baseline: 1.4202x; 1.4202x over previous
//
#include <hip/hip_runtime.h>

// Attn_60705067761886: out = softmax((enc @ W^T + b) @ h), S=32768, H=1024, fp32.
//
// Algebra: energies = enc @ (W^T h) + (b.h); the scalar b.h cancels in softmax -> b unused.
//
// Three dispatches (the round-1 cooperative fusion regressed 4x on the streaming
// phase: 1 block/CU => 8 waves/CU and VGPR_Count 56 killed MLP -> 568 GB/s.
// Reverted to many-small-blocks structure which measured ~6.4 TB/s):
//   K1: vpart[jg][k] partial sums of v = W^T h   (256 blocks -- all CUs busy)
//   K2: block-prologue reduces vpart -> LDS, then e[s] = enc[s].v  (134 MiB, HBM-bound)
//   K3: out = softmax(e)  (single block, all values in registers)

#define H 1024
#define S 32768

// ---------------- K1: vpart[jg][k] = sum_{j in group jg} W[j][k] * h[j] ----------------
// 256 blocks x 256 threads. Block (kb,jg) = (b>>2, b&3) owns columns [16kb,16kb+16)
// x rows [256jg, 256jg+256). Thread t: kk = t&15 (column), jj = t>>4 (j residue);
// loops j = j0 + 16*i + jj for i in [0,16). One wave load instruction touches
// 4 j-rows x 16 consecutive k = 4 full 64B cachelines (100% utilization).
// Reduce: shfl_xor over lane bits 4,5 (within-wave jj), LDS across 4 waves.
__global__ __launch_bounds__(256) void matvec_vpart(const float* __restrict__ W,
                                                    const float* __restrict__ h,
                                                    float* __restrict__ vpart) {
    __shared__ float sh[64];
    const int t    = threadIdx.x;
    const int kk   = t & 15;
    const int jj   = t >> 4;          // 0..15 across the block
    const int w    = t >> 6;
    const int lane = t & 63;
    const int kb   = blockIdx.x >> 2; // 0..63
    const int jg   = blockIdx.x & 3;  // 0..3
    const int k0   = kb * 16;
    const int j0   = jg * 256;

    const float* Wp = W + (size_t)(j0 + jj) * H + k0 + kk;
    const float* hp = h + j0 + jj;
    float a0 = 0.f, a1 = 0.f;
#pragma unroll
    for (int i = 0; i < 16; i += 2) {
        a0 = fmaf(Wp[(size_t)(16 * i) * H],       hp[16 * i],       a0);
        a1 = fmaf(Wp[(size_t)(16 * (i + 1)) * H], hp[16 * (i + 1)], a1);
    }
    float a = a0 + a1;
    a += __shfl_xor(a, 16, 64);   // sum the 4 jj residues within the wave
    a += __shfl_xor(a, 32, 64);
    if (lane < 16) sh[w * 16 + lane] = a;
    __syncthreads();
    if (t < 16)
        vpart[(size_t)jg * H + k0 + t] = sh[t] + sh[t + 16] + sh[t + 32] + sh[t + 48];
}

// ---------------- K2: e[s] = enc[s] . v ----------------
// 2048 blocks x 256 threads; wave handles 4 consecutive rows. All 16
// global_load_dwordx4 (64 lanes x 16 B = 1 KiB each, perfectly coalesced)
// are issued before the FMA chains for max memory-level parallelism.
// Prologue: block cooperatively sums the 4 vpart rows into LDS (16 KiB of
// L2-hot reads per block), then each wave reads its v fragment from LDS.
__global__ __launch_bounds__(256) void energies_kernel(const float* __restrict__ enc,
                                                       const float* __restrict__ vpart,
                                                       float* __restrict__ e) {
    __shared__ float shv[H];
    const int t     = threadIdx.x;
    const int wave  = t >> 6;
    const int lane  = t & 63;
    const int lane4 = lane * 4;

    {   // v[k] = sum_jg vpart[jg][k]; each thread owns 4 consecutive k
        const float4 p0 = *(const float4*)(vpart + 0 * H + t * 4);
        const float4 p1 = *(const float4*)(vpart + 1 * H + t * 4);
        const float4 p2 = *(const float4*)(vpart + 2 * H + t * 4);
        const float4 p3 = *(const float4*)(vpart + 3 * H + t * 4);
        float4 r;
        r.x = (p0.x + p1.x) + (p2.x + p3.x);
        r.y = (p0.y + p1.y) + (p2.y + p3.y);
        r.z = (p0.z + p1.z) + (p2.z + p3.z);
        r.w = (p0.w + p1.w) + (p2.w + p3.w);
        *(float4*)(shv + t * 4) = r;
    }
    __syncthreads();

    float4 vf[4];
#pragma unroll
    for (int tt = 0; tt < 4; ++tt)
        vf[tt] = *(const float4*)(shv + tt * 256 + lane4);

    const int row0 = (blockIdx.x * 4 + wave) * 4;
    const float* rp = enc + (size_t)row0 * H + lane4;

    float4 a[4][4];
#pragma unroll
    for (int r = 0; r < 4; ++r)
#pragma unroll
        for (int tt = 0; tt < 4; ++tt)
            a[r][tt] = *(const float4*)(rp + (size_t)r * H + tt * 256);

    float acc[4];
#pragma unroll
    for (int r = 0; r < 4; ++r) {
        float s = 0.f;
#pragma unroll
        for (int tt = 0; tt < 4; ++tt) {
            s = fmaf(a[r][tt].x, vf[tt].x, s);
            s = fmaf(a[r][tt].y, vf[tt].y, s);
            s = fmaf(a[r][tt].z, vf[tt].z, s);
            s = fmaf(a[r][tt].w, vf[tt].w, s);
        }
#pragma unroll
        for (int off = 32; off >= 1; off >>= 1)
            s += __shfl_xor(s, off, 64);
        acc[r] = s;
    }
    if (lane == 0)
        *(float4*)(e + row0) = make_float4(acc[0], acc[1], acc[2], acc[3]);
}

// ---------------- K3: softmax over 32768 ----------------
// Single block, 1024 threads; each thread keeps its 32 energies in registers.
__global__ __launch_bounds__(1024) void softmax_kernel(const float* __restrict__ e,
                                                       float* __restrict__ out) {
    __shared__ float red[16];
    const int t    = threadIdx.x;
    const int lane = t & 63;
    const int wv   = t >> 6;

    float4 x[8];
#pragma unroll
    for (int r = 0; r < 8; ++r)
        x[r] = *(const float4*)(e + 4 * t + 4096 * r);

    float m = -1e30f;
#pragma unroll
    for (int r = 0; r < 8; ++r)
        m = fmaxf(m, fmaxf(fmaxf(x[r].x, x[r].y), fmaxf(x[r].z, x[r].w)));
#pragma unroll
    for (int off = 32; off >= 1; off >>= 1)
        m = fmaxf(m, __shfl_xor(m, off, 64));
    if (lane == 0) red[wv] = m;
    __syncthreads();
    if (t < 16) {
        float mm = red[t];
#pragma unroll
        for (int off = 8; off >= 1; off >>= 1)
            mm = fmaxf(mm, __shfl_xor(mm, off, 64));
        if (t == 0) red[0] = mm;
    }
    __syncthreads();
    m = red[0];
    __syncthreads();  // red reused below

    float s = 0.f;
#pragma unroll
    for (int r = 0; r < 8; ++r) {
        x[r].x = __expf(x[r].x - m); s += x[r].x;
        x[r].y = __expf(x[r].y - m); s += x[r].y;
        x[r].z = __expf(x[r].z - m); s += x[r].z;
        x[r].w = __expf(x[r].w - m); s += x[r].w;
    }
#pragma unroll
    for (int off = 32; off >= 1; off >>= 1)
        s += __shfl_xor(s, off, 64);
    if (lane == 0) red[wv] = s;
    __syncthreads();
    if (t < 16) {
        float ss = red[t];
#pragma unroll
        for (int off = 8; off >= 1; off >>= 1)
            ss += __shfl_xor(ss, off, 64);
        if (t == 0) red[0] = ss;
    }
    __syncthreads();
    const float inv = 1.0f / red[0];

#pragma unroll
    for (int r = 0; r < 8; ++r) {
        float4 y;
        y.x = x[r].x * inv;
        y.y = x[r].y * inv;
        y.z = x[r].z * inv;
        y.w = x[r].w * inv;
        *(float4*)(out + 4 * t + 4096 * r) = y;
    }
}

extern "C" void kernel_launch(void* const* d_in, const int* in_sizes, int n_in,
                              void* d_out, int out_size, void* d_ws, size_t ws_size,
                              hipStream_t stream) {
    const float* h   = (const float*)d_in[0];  // [H]
    const float* enc = (const float*)d_in[1];  // [S, H]
    const float* W   = (const float*)d_in[2];  // [H, H]
    // d_in[3] = b: unused -- b.h is constant over S, cancels in softmax.

    float* vpart = (float*)d_ws;           // [4][H] floats, fully written by K1
    float* e     = (float*)d_ws + 4 * H;   // [S] floats
    float* out   = (float*)d_out;          // [S]

    matvec_vpart<<<256, 256, 0, stream>>>(W, h, vpart);
    energies_kernel<<<S / 16, 256, 0, stream>>>(enc, vpart, e);
    softmax_kernel<<<1, 1024, 0, stream>>>(e, out);
}